// Round 1
// baseline (1237.199 us; speedup 1.0000x reference)
//
#include <hip/hip_runtime.h>
#include <math.h>

#define DD 512
#define BB 8
#define NN 4096
#define HG 64
#define M_ROWS (BB * NN)           // 32768
#define ELEMS ((size_t)M_ROWS * DD)

#define BM 64
#define BN 64
#define BK 16

enum { EPI_LAM = 0, EPI_INP = 1, EPI_SIG = 2, EPI_PLAIN = 3 };

__device__ __forceinline__ float sigmoidf_(float v) { return 1.0f / (1.0f + expf(-v)); }

// C = A(Mx512) @ W(512x512) + bias, with fused epilogue.
template <int EPI>
__global__ __launch_bounds__(256) void gemm_epi(
    const float* __restrict__ A, const float* __restrict__ W,
    const float* __restrict__ bias, const float* __restrict__ aux,
    const float* __restrict__ lb_ptr, float* __restrict__ out)
{
    __shared__ __align__(16) float As[BK][BM + 1];
    __shared__ __align__(16) float Bs[BK][BN];
    const int bm = blockIdx.y * BM;
    const int bn = blockIdx.x * BN;
    const int tid = threadIdx.x;
    const int ty = tid >> 4, tx = tid & 15;
    const int a_row = tid >> 2, a_koff = (tid & 3) << 2;
    const int b_krow = tid >> 4, b_noff = (tid & 15) << 2;

    float acc[4][4] = {};
    for (int k0 = 0; k0 < DD; k0 += BK) {
        const float4 av = *(const float4*)&A[(size_t)(bm + a_row) * DD + k0 + a_koff];
        As[a_koff + 0][a_row] = av.x;
        As[a_koff + 1][a_row] = av.y;
        As[a_koff + 2][a_row] = av.z;
        As[a_koff + 3][a_row] = av.w;
        *(float4*)&Bs[b_krow][b_noff] =
            *(const float4*)&W[(size_t)(k0 + b_krow) * DD + bn + b_noff];
        __syncthreads();
#pragma unroll
        for (int kk = 0; kk < BK; ++kk) {
            float a[4], b[4];
#pragma unroll
            for (int i = 0; i < 4; ++i) a[i] = As[kk][ty * 4 + i];
#pragma unroll
            for (int j = 0; j < 4; ++j) b[j] = Bs[kk][tx * 4 + j];
#pragma unroll
            for (int i = 0; i < 4; ++i)
#pragma unroll
                for (int j = 0; j < 4; ++j) acc[i][j] = fmaf(a[i], b[j], acc[i][j]);
        }
        __syncthreads();
    }

    float lb = 0.f;
    if (EPI == EPI_LAM) lb = lb_ptr[0];
#pragma unroll
    for (int i = 0; i < 4; ++i) {
        const int row = bm + ty * 4 + i;
#pragma unroll
        for (int j = 0; j < 4; ++j) {
            const int col = bn + tx * 4 + j;
            float v = acc[i][j] + bias[col];
            float r;
            if (EPI == EPI_LAM) {
                r = lb + (1.0f - lb) * sigmoidf_(v);
            } else if (EPI == EPI_INP) {
                const float s = sigmoidf_(v);          // silu(v) = v * sigmoid(v)
                r = v * s * (1.0f - aux[(size_t)row * DD + col]);
            } else if (EPI == EPI_SIG) {
                r = sigmoidf_(v);
            } else {
                r = v;
            }
            out[(size_t)row * DD + col] = r;
        }
    }
}

// Inclusive fwd+bwd complex gated scan along j (axis 1). line = bb*64 + i.
__global__ __launch_bounds__(256) void scan_j(
    const float* __restrict__ lam, const float* __restrict__ inp,
    const float* __restrict__ theta, float* __restrict__ hidden)
{
    const int g = blockIdx.x * 256 + threadIdx.x;
    const int d = g & (DD - 1);
    const int line = g >> 9;
    const size_t base = (size_t)line * (HG * DD) + d;
    float s, c;
    sincosf(theta[d], &s, &c);

    float fr[HG];
    float yr = 0.f, yi = 0.f;
#pragma unroll
    for (int j = 0; j < HG; ++j) {
        const size_t idx = base + (size_t)j * DD;
        const float lm = lam[idx];
        const float xv = inp[idx];
        const float nr = fmaf(lm, c * yr - s * yi, xv);
        const float ni = lm * (c * yi + s * yr);
        yr = nr; yi = ni;
        fr[j] = yr;
    }
    yr = 0.f; yi = 0.f;
#pragma unroll
    for (int j = HG - 1; j >= 0; --j) {
        const size_t idx = base + (size_t)j * DD;
        const float lm = lam[idx];
        const float xv = inp[idx];
        const float nr = fmaf(lm, c * yr - s * yi, xv);
        const float ni = lm * (c * yi + s * yr);
        yr = nr; yi = ni;
        hidden[idx] = fr[j] + yr;       // fwd + bwd, first write of hidden
    }
}

// Inclusive fwd+bwd complex gated scan along i (axis 0). line = bb*64 + j.
__global__ __launch_bounds__(256) void scan_i(
    const float* __restrict__ lam, const float* __restrict__ inp,
    const float* __restrict__ theta, float* __restrict__ hidden)
{
    const int g = blockIdx.x * 256 + threadIdx.x;
    const int d = g & (DD - 1);
    const int line = g >> 9;
    const int bb = line >> 6;
    const int j = line & 63;
    const size_t base = (size_t)bb * (HG * HG * DD) + (size_t)j * DD + d;
    float s, c;
    sincosf(theta[d], &s, &c);

    float fr[HG];
    float yr = 0.f, yi = 0.f;
#pragma unroll
    for (int i = 0; i < HG; ++i) {
        const size_t idx = base + (size_t)i * (HG * DD);
        const float lm = lam[idx];
        const float xv = inp[idx];
        const float nr = fmaf(lm, c * yr - s * yi, xv);
        const float ni = lm * (c * yi + s * yr);
        yr = nr; yi = ni;
        fr[i] = yr;
    }
    yr = 0.f; yi = 0.f;
#pragma unroll
    for (int i = HG - 1; i >= 0; --i) {
        const size_t idx = base + (size_t)i * (HG * DD);
        const float lm = lam[idx];
        const float xv = inp[idx];
        const float nr = fmaf(lm, c * yr - s * yi, xv);
        const float ni = lm * (c * yi + s * yr);
        yr = nr; yi = ni;
        hidden[idx] += fr[i] + yr;      // accumulate onto axis-1 result
    }
}

// v = g * hidden * rsqrt(mean(hidden^2) + 1e-6), one block per row of 512.
__global__ __launch_bounds__(256) void gate_rmsnorm(
    const float* __restrict__ hidden, const float* __restrict__ g,
    float* __restrict__ v)
{
    const int row = blockIdx.x;
    const int t = threadIdx.x;
    const size_t b0 = (size_t)row * DD + t;
    const float h0 = hidden[b0];
    const float h1 = hidden[b0 + 256];
    float ss = h0 * h0 + h1 * h1;
#pragma unroll
    for (int off = 32; off > 0; off >>= 1) ss += __shfl_down(ss, off, 64);
    __shared__ float wsum[4];
    __shared__ float rms_s;
    if ((t & 63) == 0) wsum[t >> 6] = ss;
    __syncthreads();
    if (t == 0) {
        const float tot = wsum[0] + wsum[1] + wsum[2] + wsum[3];
        rms_s = rsqrtf(tot * (1.0f / (float)DD) + 1e-6f);
    }
    __syncthreads();
    const float rms = rms_s;
    v[b0] = g[b0] * h0 * rms;
    v[b0 + 256] = g[b0 + 256] * h1 * rms;
}

extern "C" void kernel_launch(void* const* d_in, const int* in_sizes, int n_in,
                              void* d_out, int out_size, void* d_ws, size_t ws_size,
                              hipStream_t stream)
{
    const float* x     = (const float*)d_in[0];
    const float* lb    = (const float*)d_in[1];
    const float* W_in  = (const float*)d_in[2];
    const float* b_in  = (const float*)d_in[3];
    const float* W_f   = (const float*)d_in[4];
    const float* b_f   = (const float*)d_in[5];
    const float* theta = (const float*)d_in[6];
    const float* W_g   = (const float*)d_in[7];
    const float* b_g   = (const float*)d_in[8];
    const float* W_out = (const float*)d_in[9];
    const float* b_out = (const float*)d_in[10];

    float* out = (float*)d_out;
    float* ws  = (float*)d_ws;

    float* lam_buf = ws;             // 64 MB: lam, later reused for g
    float* inp_buf = ws + ELEMS;     // 64 MB: inp, later reused for v
    float* hidden  = out;            // hidden lives in d_out until final GEMM

    const dim3 gg(DD / BN, M_ROWS / BM);   // (8, 512)

    // lam = lb + (1-lb)*sigmoid(x @ W_f + b_f)
    gemm_epi<EPI_LAM><<<gg, 256, 0, stream>>>(x, W_f, b_f, nullptr, lb, lam_buf);
    // inp = silu(x @ W_in + b_in) * (1 - lam)
    gemm_epi<EPI_INP><<<gg, 256, 0, stream>>>(x, W_in, b_in, lam_buf, nullptr, inp_buf);
    // hidden = scan_j(fwd)+scan_j(bwd); then += scan_i(fwd)+scan_i(bwd)
    scan_j<<<1024, 256, 0, stream>>>(lam_buf, inp_buf, theta, hidden);
    scan_i<<<1024, 256, 0, stream>>>(lam_buf, inp_buf, theta, hidden);
    // g = sigmoid(x @ W_g + b_g)  (lam buffer is free now)
    gemm_epi<EPI_SIG><<<gg, 256, 0, stream>>>(x, W_g, b_g, nullptr, nullptr, lam_buf);
    // v = g * rmsnorm(hidden)  (inp buffer is free now)
    gate_rmsnorm<<<M_ROWS, 256, 0, stream>>>(hidden, lam_buf, inp_buf);
    // out = v @ W_out + b_out  (overwrites hidden in d_out)
    gemm_epi<EPI_PLAIN><<<gg, 256, 0, stream>>>(inp_buf, W_out, b_out, nullptr, nullptr, out);
}

// Round 2
// 447.894 us; speedup vs baseline: 2.7623x; 2.7623x over previous
//
#include <hip/hip_runtime.h>
#include <hip/hip_bf16.h>
#include <math.h>

#define DD 512
#define BBATCH 8
#define HG 64
#define M_ROWS (BBATCH * HG * HG)      // 32768
#define ELEMS ((size_t)M_ROWS * DD)

typedef __attribute__((ext_vector_type(8))) short bf16x8;
typedef __attribute__((ext_vector_type(4))) float f32x4;

enum { EPI_LAM = 0, EPI_INP = 1, EPI_SIG = 2, EPI_PLAIN = 3 };

__device__ __forceinline__ float sigmoidf_(float v) { return 1.0f / (1.0f + expf(-v)); }

// Transpose + convert one 512x512 fp32 W (K,N) -> bf16 W^T (N,K).
__global__ __launch_bounds__(256) void wtrans(const float* __restrict__ W,
                                              __hip_bfloat16* __restrict__ WT)
{
    __shared__ float tile[64][65];
    const int n0 = blockIdx.x * 64, k0 = blockIdx.y * 64;
    const int t = threadIdx.x;
    const int tr = t >> 6, tc = t & 63;
#pragma unroll
    for (int p = 0; p < 16; ++p) {
        const int kk = p * 4 + tr;
        tile[kk][tc] = W[(size_t)(k0 + kk) * DD + n0 + tc];
    }
    __syncthreads();
#pragma unroll
    for (int p = 0; p < 16; ++p) {
        const int nn = p * 4 + tr;
        WT[(size_t)(n0 + nn) * DD + k0 + tc] = __float2bfloat16(tile[tc][nn]);
    }
}

// C = A(Mx512) @ WT^T + bias with fused epilogue. 128x128 tile, BK=32,
// 4 waves in 2x2, each wave = 4x4 grid of 16x16x32 bf16 MFMA.
// A_BF16: A already bf16 (async-staged); else fp32 -> cvt during staging.
template <int EPI, bool A_BF16>
__global__ __launch_bounds__(256) void gemm_mfma(
    const void* __restrict__ Aptr,
    const __hip_bfloat16* __restrict__ WT,
    const float* __restrict__ bias,
    const float* __restrict__ aux,      // lam for EPI_INP
    const float* __restrict__ lb_ptr,   // for EPI_LAM
    void* __restrict__ outp)
{
    __shared__ __align__(16) __hip_bfloat16 As[128][32];
    __shared__ __align__(16) __hip_bfloat16 Bs[128][32];

    const int tid  = threadIdx.x;
    const int wave = tid >> 6;
    const int lane = tid & 63;
    const int wm = wave >> 1, wn = wave & 1;
    const int lrow = lane & 15;          // m/n within a 16-tile
    const int lk   = lane >> 4;          // k-group 0..3

    const int m0 = blockIdx.y * 128;
    const int n0 = blockIdx.x * 128;

    const int srow  = lane >> 2;         // async staging: row within 16-row chunk
    const int skoff = (lane & 3) * 8;    // element offset within row

    f32x4 acc[4][4];
#pragma unroll
    for (int i = 0; i < 4; ++i)
#pragma unroll
        for (int j = 0; j < 4; ++j) acc[i][j] = (f32x4)(0.f);

    const float* Af = (const float*)Aptr;
    const __hip_bfloat16* Ab = (const __hip_bfloat16*)Aptr;
    const int ar  = tid >> 1;            // fp32 staging: row 0..127
    const int akh = (tid & 1) << 4;      // k-half offset 0/16 (elements)

    for (int k0 = 0; k0 < DD; k0 += 32) {
        // ---- stage B: async bf16, 2 x 1KB per wave ----
#pragma unroll
        for (int i = 0; i < 2; ++i) {
            const int row = wave * 32 + i * 16;
            const __hip_bfloat16* src = WT + (size_t)(n0 + row + srow) * DD + k0 + skoff;
            __builtin_amdgcn_global_load_lds(
                (const __attribute__((address_space(1))) void*)src,
                (__attribute__((address_space(3))) void*)&Bs[row][0], 16, 0, 0);
        }
        // ---- stage A ----
        if (A_BF16) {
#pragma unroll
            for (int i = 0; i < 2; ++i) {
                const int row = wave * 32 + i * 16;
                const __hip_bfloat16* src = Ab + (size_t)(m0 + row + srow) * DD + k0 + skoff;
                __builtin_amdgcn_global_load_lds(
                    (const __attribute__((address_space(1))) void*)src,
                    (__attribute__((address_space(3))) void*)&As[row][0], 16, 0, 0);
            }
        } else {
            const float* srcrow = Af + (size_t)(m0 + ar) * DD + k0 + akh;
            float fl[16];
            *(float4*)&fl[0]  = ((const float4*)srcrow)[0];
            *(float4*)&fl[4]  = ((const float4*)srcrow)[1];
            *(float4*)&fl[8]  = ((const float4*)srcrow)[2];
            *(float4*)&fl[12] = ((const float4*)srcrow)[3];
            __hip_bfloat16 hb[16];
#pragma unroll
            for (int i = 0; i < 16; ++i) hb[i] = __float2bfloat16(fl[i]);
            *(int4*)&As[ar][akh]     = ((int4*)hb)[0];
            *(int4*)&As[ar][akh + 8] = ((int4*)hb)[1];
        }
        __syncthreads();
        // ---- compute: 8 ds_read_b128 + 16 MFMA per wave ----
        bf16x8 afr[4], bfr[4];
#pragma unroll
        for (int t = 0; t < 4; ++t) {
            afr[t] = *(const bf16x8*)&As[wm * 64 + t * 16 + lrow][lk * 8];
            bfr[t] = *(const bf16x8*)&Bs[wn * 64 + t * 16 + lrow][lk * 8];
        }
#pragma unroll
        for (int mt = 0; mt < 4; ++mt)
#pragma unroll
            for (int nt = 0; nt < 4; ++nt)
                acc[mt][nt] = __builtin_amdgcn_mfma_f32_16x16x32_bf16(
                    afr[mt], bfr[nt], acc[mt][nt], 0, 0, 0);
        __syncthreads();
    }

    // ---- epilogue: C/D layout col=lane&15, row=(lane>>4)*4+reg ----
    const float lb = (EPI == EPI_LAM) ? lb_ptr[0] : 0.f;
#pragma unroll
    for (int mt = 0; mt < 4; ++mt) {
#pragma unroll
        for (int nt = 0; nt < 4; ++nt) {
            const int col = n0 + wn * 64 + nt * 16 + lrow;
            const float bcol = bias[col];
#pragma unroll
            for (int r = 0; r < 4; ++r) {
                const int row = m0 + wm * 64 + mt * 16 + lk * 4 + r;
                const float v = acc[mt][nt][r] + bcol;
                if (EPI == EPI_LAM) {
                    ((float*)outp)[(size_t)row * DD + col] = lb + (1.0f - lb) * sigmoidf_(v);
                } else if (EPI == EPI_INP) {
                    const float s = sigmoidf_(v);   // silu = v*sigmoid(v)
                    const float lm = aux[(size_t)row * DD + col];
                    ((__hip_bfloat16*)outp)[(size_t)row * DD + col] =
                        __float2bfloat16(v * s * (1.0f - lm));
                } else if (EPI == EPI_SIG) {
                    ((float*)outp)[(size_t)row * DD + col] = sigmoidf_(v);
                } else {
                    ((float*)outp)[(size_t)row * DD + col] = v;
                }
            }
        }
    }
}

// Inclusive fwd+bwd complex gated scan along j (axis 1). line = bb*64 + i.
__global__ __launch_bounds__(256) void scan_j(
    const float* __restrict__ lam, const __hip_bfloat16* __restrict__ inp,
    const float* __restrict__ theta, float* __restrict__ hidden)
{
    const int g = blockIdx.x * 256 + threadIdx.x;
    const int d = g & (DD - 1);
    const int line = g >> 9;
    const size_t base = (size_t)line * (HG * DD) + d;
    float s, c;
    sincosf(theta[d], &s, &c);

    float fr[HG];
    float yr = 0.f, yi = 0.f;
#pragma unroll
    for (int j = 0; j < HG; ++j) {
        const size_t idx = base + (size_t)j * DD;
        const float lm = lam[idx];
        const float xv = __bfloat162float(inp[idx]);
        const float nr = fmaf(lm, c * yr - s * yi, xv);
        const float ni = lm * (c * yi + s * yr);
        yr = nr; yi = ni;
        fr[j] = yr;
    }
    yr = 0.f; yi = 0.f;
#pragma unroll
    for (int j = HG - 1; j >= 0; --j) {
        const size_t idx = base + (size_t)j * DD;
        const float lm = lam[idx];
        const float xv = __bfloat162float(inp[idx]);
        const float nr = fmaf(lm, c * yr - s * yi, xv);
        const float ni = lm * (c * yi + s * yr);
        yr = nr; yi = ni;
        hidden[idx] = fr[j] + yr;
    }
}

// Inclusive fwd+bwd complex gated scan along i (axis 0). line = bb*64 + j.
__global__ __launch_bounds__(256) void scan_i(
    const float* __restrict__ lam, const __hip_bfloat16* __restrict__ inp,
    const float* __restrict__ theta, float* __restrict__ hidden)
{
    const int g = blockIdx.x * 256 + threadIdx.x;
    const int d = g & (DD - 1);
    const int line = g >> 9;
    const int bb = line >> 6;
    const int j = line & 63;
    const size_t base = (size_t)bb * (HG * HG * DD) + (size_t)j * DD + d;
    float s, c;
    sincosf(theta[d], &s, &c);

    float fr[HG];
    float yr = 0.f, yi = 0.f;
#pragma unroll
    for (int i = 0; i < HG; ++i) {
        const size_t idx = base + (size_t)i * (HG * DD);
        const float lm = lam[idx];
        const float xv = __bfloat162float(inp[idx]);
        const float nr = fmaf(lm, c * yr - s * yi, xv);
        const float ni = lm * (c * yi + s * yr);
        yr = nr; yi = ni;
        fr[i] = yr;
    }
    yr = 0.f; yi = 0.f;
#pragma unroll
    for (int i = HG - 1; i >= 0; --i) {
        const size_t idx = base + (size_t)i * (HG * DD);
        const float lm = lam[idx];
        const float xv = __bfloat162float(inp[idx]);
        const float nr = fmaf(lm, c * yr - s * yi, xv);
        const float ni = lm * (c * yi + s * yr);
        yr = nr; yi = ni;
        hidden[idx] += fr[i] + yr;
    }
}

// v = g * hidden * rsqrt(mean(hidden^2)+1e-6), bf16 out. One block per row.
__global__ __launch_bounds__(256) void gate_rmsnorm(
    const float* __restrict__ hidden, const float* __restrict__ g,
    __hip_bfloat16* __restrict__ v)
{
    const int row = blockIdx.x;
    const int t = threadIdx.x;
    const size_t b0 = (size_t)row * DD + t;
    const float h0 = hidden[b0];
    const float h1 = hidden[b0 + 256];
    float ss = h0 * h0 + h1 * h1;
#pragma unroll
    for (int off = 32; off > 0; off >>= 1) ss += __shfl_down(ss, off, 64);
    __shared__ float wsum[4];
    __shared__ float rms_s;
    if ((t & 63) == 0) wsum[t >> 6] = ss;
    __syncthreads();
    if (t == 0) {
        const float tot = wsum[0] + wsum[1] + wsum[2] + wsum[3];
        rms_s = rsqrtf(tot * (1.0f / (float)DD) + 1e-6f);
    }
    __syncthreads();
    const float rms = rms_s;
    v[b0]       = __float2bfloat16(g[b0] * h0 * rms);
    v[b0 + 256] = __float2bfloat16(g[b0 + 256] * h1 * rms);
}

extern "C" void kernel_launch(void* const* d_in, const int* in_sizes, int n_in,
                              void* d_out, int out_size, void* d_ws, size_t ws_size,
                              hipStream_t stream)
{
    const float* x     = (const float*)d_in[0];
    const float* lb    = (const float*)d_in[1];
    const float* W_in  = (const float*)d_in[2];
    const float* b_in  = (const float*)d_in[3];
    const float* W_f   = (const float*)d_in[4];
    const float* b_f   = (const float*)d_in[5];
    const float* theta = (const float*)d_in[6];
    const float* W_g   = (const float*)d_in[7];
    const float* b_g   = (const float*)d_in[8];
    const float* W_out = (const float*)d_in[9];
    const float* b_out = (const float*)d_in[10];

    float* out = (float*)d_out;
    char* wsb  = (char*)d_ws;

    // ws layout (peak 98 MB): [0,64M): lam f32 (later g f32)
    //                         [64M,96M): inp bf16 (later v bf16)
    //                         [96M,98M): 4 x W^T bf16
    float* lam_g = (float*)wsb;
    __hip_bfloat16* inp_v = (__hip_bfloat16*)(wsb + ELEMS * 4);
    __hip_bfloat16* WTf  = (__hip_bfloat16*)(wsb + ELEMS * 6);
    __hip_bfloat16* WTin = WTf  + (size_t)DD * DD;
    __hip_bfloat16* WTg  = WTin + (size_t)DD * DD;
    __hip_bfloat16* WTo  = WTg  + (size_t)DD * DD;
    float* hidden = out;   // hidden lives in d_out until the final GEMM

    const dim3 tg(8, 8);
    wtrans<<<tg, 256, 0, stream>>>(W_f,   WTf);
    wtrans<<<tg, 256, 0, stream>>>(W_in,  WTin);
    wtrans<<<tg, 256, 0, stream>>>(W_g,   WTg);
    wtrans<<<tg, 256, 0, stream>>>(W_out, WTo);

    const dim3 gg(DD / 128, M_ROWS / 128);   // (4, 256)
    // lam = lb + (1-lb)*sigmoid(x@W_f + b_f)
    gemm_mfma<EPI_LAM, false><<<gg, 256, 0, stream>>>(x, WTf, b_f, nullptr, lb, lam_g);
    // inp = silu(x@W_in + b_in) * (1-lam)   [bf16]
    gemm_mfma<EPI_INP, false><<<gg, 256, 0, stream>>>(x, WTin, b_in, lam_g, nullptr, inp_v);
    // bidirectional 2D scans -> hidden (d_out)
    scan_j<<<1024, 256, 0, stream>>>(lam_g, inp_v, theta, hidden);
    scan_i<<<1024, 256, 0, stream>>>(lam_g, inp_v, theta, hidden);
    // g = sigmoid(x@W_g + b_g)  (lam dead -> reuse its buffer)
    gemm_mfma<EPI_SIG, false><<<gg, 256, 0, stream>>>(x, WTg, b_g, nullptr, nullptr, lam_g);
    // v = g * rmsnorm(hidden)   [bf16] (inp dead -> reuse its buffer)
    gate_rmsnorm<<<M_ROWS, 256, 0, stream>>>(hidden, lam_g, inp_v);
    // out = v @ W_out + b_out   (overwrites hidden in d_out)
    gemm_mfma<EPI_PLAIN, true><<<gg, 256, 0, stream>>>(inp_v, WTo, b_out, nullptr, nullptr, out);
}

// Round 3
// 419.305 us; speedup vs baseline: 2.9506x; 1.0682x over previous
//
#include <hip/hip_runtime.h>
#include <math.h>

#define DD 512
#define HG 64
#define M_ROWS 32768                    // 8*64*64
#define ELEMS ((size_t)M_ROWS * DD)

typedef __attribute__((ext_vector_type(8))) _Float16 f16x8;
typedef __attribute__((ext_vector_type(4))) float f32x4;

__device__ __forceinline__ float sigmoidf_(float v) { return 1.0f / (1.0f + expf(-v)); }

// Transpose + convert one 512x512 fp32 W (K,N) -> fp16 W^T (N,K).
__global__ __launch_bounds__(256) void wtrans(const float* __restrict__ W,
                                              _Float16* __restrict__ WT)
{
    __shared__ float tile[64][65];
    const int n0 = blockIdx.x * 64, k0 = blockIdx.y * 64;
    const int t = threadIdx.x;
    const int tr = t >> 6, tc = t & 63;
#pragma unroll
    for (int p = 0; p < 16; ++p) {
        const int kk = p * 4 + tr;
        tile[kk][tc] = W[(size_t)(k0 + kk) * DD + n0 + tc];
    }
    __syncthreads();
#pragma unroll
    for (int p = 0; p < 16; ++p) {
        const int nn = p * 4 + tr;
        WT[(size_t)(n0 + nn) * DD + k0 + tc] = (_Float16)tile[tc][nn];
    }
}

// Fused: C = x(32768x512 f32) @ [W_f|W_in|W_g]^T + bias, N=1536.
// seg 0 -> dm = (1-lb)*sigmoid(-v)  [fp16]
// seg 1 -> u  = silu(v)             [fp16]
// seg 2 -> g  = sigmoid(v)          [fp16]
// 128x128 tile, BK=32, 4 waves 2x2, each 4x4 of 16x16x32 f16 MFMA.
__global__ __launch_bounds__(256) void gemm_fused(
    const float* __restrict__ A, const _Float16* __restrict__ WT,
    const float* __restrict__ b_f, const float* __restrict__ b_in,
    const float* __restrict__ b_g, const float* __restrict__ lb_ptr,
    _Float16* __restrict__ dm, _Float16* __restrict__ u, _Float16* __restrict__ g)
{
    __shared__ __align__(16) _Float16 As[128][32];
    __shared__ __align__(16) _Float16 Bs[128][32];

    const int tid  = threadIdx.x;
    const int wave = tid >> 6;
    const int lane = tid & 63;
    const int wm = wave >> 1, wn = wave & 1;
    const int lrow = lane & 15;
    const int lk   = lane >> 4;
    const int m0 = blockIdx.y * 128;
    const int n0 = blockIdx.x * 128;          // global fused column base

    const int srow  = lane >> 2;              // async B staging
    const int skoff = (lane & 3) * 8;
    const int ar  = tid >> 1;                 // fp32 A staging: row 0..127
    const int akh = (tid & 1) << 4;           // k-half 0/16

    f32x4 acc[4][4];
#pragma unroll
    for (int i = 0; i < 4; ++i)
#pragma unroll
        for (int j = 0; j < 4; ++j) acc[i][j] = (f32x4)(0.f);

    for (int k0 = 0; k0 < DD; k0 += 32) {
        // B: async fp16, 2 x 1KB per wave
#pragma unroll
        for (int i = 0; i < 2; ++i) {
            const int row = wave * 32 + i * 16;
            const _Float16* src = WT + (size_t)(n0 + row + srow) * DD + k0 + skoff;
            __builtin_amdgcn_global_load_lds(
                (const __attribute__((address_space(1))) void*)src,
                (__attribute__((address_space(3))) void*)&Bs[row][0], 16, 0, 0);
        }
        // A: fp32 -> fp16 in-register staging
        {
            const float* srcrow = A + (size_t)(m0 + ar) * DD + k0 + akh;
            float fl[16];
            *(float4*)&fl[0]  = ((const float4*)srcrow)[0];
            *(float4*)&fl[4]  = ((const float4*)srcrow)[1];
            *(float4*)&fl[8]  = ((const float4*)srcrow)[2];
            *(float4*)&fl[12] = ((const float4*)srcrow)[3];
            _Float16 hb[16];
#pragma unroll
            for (int i = 0; i < 16; ++i) hb[i] = (_Float16)fl[i];
            *(int4*)&As[ar][akh]     = ((int4*)hb)[0];
            *(int4*)&As[ar][akh + 8] = ((int4*)hb)[1];
        }
        __syncthreads();
        f16x8 afr[4], bfr[4];
#pragma unroll
        for (int t = 0; t < 4; ++t) {
            afr[t] = *(const f16x8*)&As[wm * 64 + t * 16 + lrow][lk * 8];
            bfr[t] = *(const f16x8*)&Bs[wn * 64 + t * 16 + lrow][lk * 8];
        }
#pragma unroll
        for (int mt = 0; mt < 4; ++mt)
#pragma unroll
            for (int nt = 0; nt < 4; ++nt)
                acc[mt][nt] = __builtin_amdgcn_mfma_f32_16x16x32_f16(
                    afr[mt], bfr[nt], acc[mt][nt], 0, 0, 0);
        __syncthreads();
    }

    const int seg = blockIdx.x >> 2;          // 128-col blocks, 4 per segment
    const float lb = lb_ptr[0];
    const float* bias = (seg == 0) ? b_f : (seg == 1) ? b_in : b_g;
    _Float16* outp    = (seg == 0) ? dm  : (seg == 1) ? u    : g;
    const int cbase = (n0 & 511) + wn * 64;   // column base within segment

#pragma unroll
    for (int mt = 0; mt < 4; ++mt) {
#pragma unroll
        for (int nt = 0; nt < 4; ++nt) {
            const int col = cbase + nt * 16 + lrow;
            const float bcol = bias[col];
#pragma unroll
            for (int r = 0; r < 4; ++r) {
                const int row = m0 + wm * 64 + mt * 16 + lk * 4 + r;
                const float v = acc[mt][nt][r] + bcol;
                float res;
                if (seg == 0)      res = (1.0f - lb) * sigmoidf_(-v);  // dm = 1-lam
                else if (seg == 1) res = v * sigmoidf_(v);             // silu
                else               res = sigmoidf_(v);
                outp[(size_t)row * DD + col] = (_Float16)res;
            }
        }
    }
}

// Tail: out = v(fp16) @ W_out^T + b_out, f32 out. Pure async staging.
__global__ __launch_bounds__(256) void gemm_tail(
    const _Float16* __restrict__ A, const _Float16* __restrict__ WT,
    const float* __restrict__ bias, float* __restrict__ outp)
{
    __shared__ __align__(16) _Float16 As[128][32];
    __shared__ __align__(16) _Float16 Bs[128][32];
    const int tid  = threadIdx.x;
    const int wave = tid >> 6;
    const int lane = tid & 63;
    const int wm = wave >> 1, wn = wave & 1;
    const int lrow = lane & 15;
    const int lk   = lane >> 4;
    const int m0 = blockIdx.y * 128;
    const int n0 = blockIdx.x * 128;
    const int srow  = lane >> 2;
    const int skoff = (lane & 3) * 8;

    f32x4 acc[4][4];
#pragma unroll
    for (int i = 0; i < 4; ++i)
#pragma unroll
        for (int j = 0; j < 4; ++j) acc[i][j] = (f32x4)(0.f);

    for (int k0 = 0; k0 < DD; k0 += 32) {
#pragma unroll
        for (int i = 0; i < 2; ++i) {
            const int row = wave * 32 + i * 16;
            const _Float16* bsrc = WT + (size_t)(n0 + row + srow) * DD + k0 + skoff;
            __builtin_amdgcn_global_load_lds(
                (const __attribute__((address_space(1))) void*)bsrc,
                (__attribute__((address_space(3))) void*)&Bs[row][0], 16, 0, 0);
            const _Float16* asrc = A + (size_t)(m0 + row + srow) * DD + k0 + skoff;
            __builtin_amdgcn_global_load_lds(
                (const __attribute__((address_space(1))) void*)asrc,
                (__attribute__((address_space(3))) void*)&As[row][0], 16, 0, 0);
        }
        __syncthreads();
        f16x8 afr[4], bfr[4];
#pragma unroll
        for (int t = 0; t < 4; ++t) {
            afr[t] = *(const f16x8*)&As[wm * 64 + t * 16 + lrow][lk * 8];
            bfr[t] = *(const f16x8*)&Bs[wn * 64 + t * 16 + lrow][lk * 8];
        }
#pragma unroll
        for (int mt = 0; mt < 4; ++mt)
#pragma unroll
            for (int nt = 0; nt < 4; ++nt)
                acc[mt][nt] = __builtin_amdgcn_mfma_f32_16x16x32_f16(
                    afr[mt], bfr[nt], acc[mt][nt], 0, 0, 0);
        __syncthreads();
    }
#pragma unroll
    for (int mt = 0; mt < 4; ++mt) {
#pragma unroll
        for (int nt = 0; nt < 4; ++nt) {
            const int col = n0 + wn * 64 + nt * 16 + lrow;
            const float bcol = bias[col];
#pragma unroll
            for (int r = 0; r < 4; ++r) {
                const int row = m0 + wm * 64 + mt * 16 + lk * 4 + r;
                outp[(size_t)row * DD + col] = acc[mt][nt][r] + bcol;
            }
        }
    }
}

// Inclusive fwd+bwd complex gated scan along j. lam = 1-dm, inp = dm*u.
__global__ __launch_bounds__(256) void scan_j(
    const _Float16* __restrict__ dm, const _Float16* __restrict__ u,
    const float* __restrict__ theta, float* __restrict__ hidden)
{
    const int g = blockIdx.x * 256 + threadIdx.x;
    const int d = g & (DD - 1);
    const int line = g >> 9;
    const size_t base = (size_t)line * (HG * DD) + d;
    float s, c;
    sincosf(theta[d], &s, &c);

    float fr[HG];
    float yr = 0.f, yi = 0.f;
#pragma unroll
    for (int j = 0; j < HG; ++j) {
        const size_t idx = base + (size_t)j * DD;
        const float dmv = (float)dm[idx];
        const float lm = 1.0f - dmv;
        const float xv = dmv * (float)u[idx];
        const float nr = fmaf(lm, c * yr - s * yi, xv);
        const float ni = lm * (c * yi + s * yr);
        yr = nr; yi = ni;
        fr[j] = yr;
    }
    yr = 0.f; yi = 0.f;
#pragma unroll
    for (int j = HG - 1; j >= 0; --j) {
        const size_t idx = base + (size_t)j * DD;
        const float dmv = (float)dm[idx];
        const float lm = 1.0f - dmv;
        const float xv = dmv * (float)u[idx];
        const float nr = fmaf(lm, c * yr - s * yi, xv);
        const float ni = lm * (c * yi + s * yr);
        yr = nr; yi = ni;
        hidden[idx] = fr[j] + yr;
    }
}

// Inclusive fwd+bwd complex gated scan along i, accumulating.
__global__ __launch_bounds__(256) void scan_i(
    const _Float16* __restrict__ dm, const _Float16* __restrict__ u,
    const float* __restrict__ theta, float* __restrict__ hidden)
{
    const int g = blockIdx.x * 256 + threadIdx.x;
    const int d = g & (DD - 1);
    const int line = g >> 9;
    const int bb = line >> 6;
    const int j = line & 63;
    const size_t base = (size_t)bb * (HG * HG * DD) + (size_t)j * DD + d;
    float s, c;
    sincosf(theta[d], &s, &c);

    float fr[HG];
    float yr = 0.f, yi = 0.f;
#pragma unroll
    for (int i = 0; i < HG; ++i) {
        const size_t idx = base + (size_t)i * (HG * DD);
        const float dmv = (float)dm[idx];
        const float lm = 1.0f - dmv;
        const float xv = dmv * (float)u[idx];
        const float nr = fmaf(lm, c * yr - s * yi, xv);
        const float ni = lm * (c * yi + s * yr);
        yr = nr; yi = ni;
        fr[i] = yr;
    }
    yr = 0.f; yi = 0.f;
#pragma unroll
    for (int i = HG - 1; i >= 0; --i) {
        const size_t idx = base + (size_t)i * (HG * DD);
        const float dmv = (float)dm[idx];
        const float lm = 1.0f - dmv;
        const float xv = dmv * (float)u[idx];
        const float nr = fmaf(lm, c * yr - s * yi, xv);
        const float ni = lm * (c * yi + s * yr);
        yr = nr; yi = ni;
        hidden[idx] += fr[i] + yr;
    }
}

// v = g * hidden * rsqrt(mean(hidden^2)+1e-6), fp16 out. One block per row.
__global__ __launch_bounds__(256) void gate_rmsnorm(
    const float* __restrict__ hidden, const _Float16* __restrict__ g,
    _Float16* __restrict__ v)
{
    const int row = blockIdx.x;
    const int t = threadIdx.x;
    const size_t b0 = (size_t)row * DD + t;
    const float h0 = hidden[b0];
    const float h1 = hidden[b0 + 256];
    float ss = h0 * h0 + h1 * h1;
#pragma unroll
    for (int off = 32; off > 0; off >>= 1) ss += __shfl_down(ss, off, 64);
    __shared__ float wsum[4];
    __shared__ float rms_s;
    if ((t & 63) == 0) wsum[t >> 6] = ss;
    __syncthreads();
    if (t == 0) {
        const float tot = wsum[0] + wsum[1] + wsum[2] + wsum[3];
        rms_s = rsqrtf(tot * (1.0f / (float)DD) + 1e-6f);
    }
    __syncthreads();
    const float rms = rms_s;
    v[b0]       = (_Float16)((float)g[b0] * h0 * rms);
    v[b0 + 256] = (_Float16)((float)g[b0 + 256] * h1 * rms);
}

extern "C" void kernel_launch(void* const* d_in, const int* in_sizes, int n_in,
                              void* d_out, int out_size, void* d_ws, size_t ws_size,
                              hipStream_t stream)
{
    const float* x     = (const float*)d_in[0];
    const float* lb    = (const float*)d_in[1];
    const float* W_in  = (const float*)d_in[2];
    const float* b_in  = (const float*)d_in[3];
    const float* W_f   = (const float*)d_in[4];
    const float* b_f   = (const float*)d_in[5];
    const float* theta = (const float*)d_in[6];
    const float* W_g   = (const float*)d_in[7];
    const float* b_g   = (const float*)d_in[8];
    const float* W_out = (const float*)d_in[9];
    const float* b_out = (const float*)d_in[10];

    float* out = (float*)d_out;
    char* wsb  = (char*)d_ws;

    // ws (98 MB, proven-fits): [0,32M) dm fp16 (later v fp16)
    //                          [32M,64M) u fp16
    //                          [64M,96M) g fp16
    //                          [96M,98M) WTcat fp16 [2048][512]
    _Float16* dm_v = (_Float16*)wsb;
    _Float16* u_b  = (_Float16*)(wsb + ELEMS * 2);
    _Float16* g_b  = (_Float16*)(wsb + ELEMS * 4);
    _Float16* WT   = (_Float16*)(wsb + ELEMS * 6);
    const size_t WSEG = (size_t)DD * DD;
    float* hidden = out;   // hidden lives in d_out until the tail GEMM

    const dim3 tg(8, 8);
    wtrans<<<tg, 256, 0, stream>>>(W_f,   WT);             // seg 0 -> dm
    wtrans<<<tg, 256, 0, stream>>>(W_in,  WT + WSEG);      // seg 1 -> u
    wtrans<<<tg, 256, 0, stream>>>(W_g,   WT + 2 * WSEG);  // seg 2 -> g
    wtrans<<<tg, 256, 0, stream>>>(W_out, WT + 3 * WSEG);  // tail

    gemm_fused<<<dim3(12, 256), 256, 0, stream>>>(
        x, WT, b_f, b_in, b_g, lb, dm_v, u_b, g_b);

    scan_j<<<1024, 256, 0, stream>>>(dm_v, u_b, theta, hidden);
    scan_i<<<1024, 256, 0, stream>>>(dm_v, u_b, theta, hidden);

    // v overwrites dm (dead after scan_i)
    gate_rmsnorm<<<M_ROWS, 256, 0, stream>>>(hidden, g_b, dm_v);

    gemm_tail<<<dim3(4, 256), 256, 0, stream>>>(dm_v, WT + 3 * WSEG, b_out, out);
}

// Round 4
// 360.569 us; speedup vs baseline: 3.4312x; 1.1629x over previous
//
#include <hip/hip_runtime.h>
#include <math.h>

#define DD 512
#define HG 64
#define M_ROWS 32768                    // 8*64*64
#define ELEMS ((size_t)M_ROWS * DD)

typedef __attribute__((ext_vector_type(8))) _Float16 f16x8;
typedef __attribute__((ext_vector_type(4))) float f32x4;

__device__ __forceinline__ float sigmoidf_(float v) { return 1.0f / (1.0f + expf(-v)); }

// x fp32 -> fp16, 8 elems/thread.
__global__ __launch_bounds__(256) void cvt_x(const float* __restrict__ x,
                                             _Float16* __restrict__ x16)
{
    const size_t i = ((size_t)blockIdx.x * 256 + threadIdx.x) * 8;
    const float4 a = *(const float4*)&x[i];
    const float4 b = *(const float4*)&x[i + 4];
    f16x8 h;
    h[0] = (_Float16)a.x; h[1] = (_Float16)a.y; h[2] = (_Float16)a.z; h[3] = (_Float16)a.w;
    h[4] = (_Float16)b.x; h[5] = (_Float16)b.y; h[6] = (_Float16)b.z; h[7] = (_Float16)b.w;
    *(f16x8*)&x16[i] = h;
}

// Transpose + convert 512x512 fp32 W (K,N) -> fp16 W^T (N,K). z picks which W.
__global__ __launch_bounds__(256) void wtrans4(
    const float* __restrict__ W0, const float* __restrict__ W1,
    const float* __restrict__ W2, const float* __restrict__ W3,
    _Float16* __restrict__ WT)
{
    const float* W = (blockIdx.z == 0) ? W0 : (blockIdx.z == 1) ? W1
                   : (blockIdx.z == 2) ? W2 : W3;
    _Float16* dst = WT + (size_t)blockIdx.z * DD * DD;
    __shared__ float tile[64][65];
    const int n0 = blockIdx.x * 64, k0 = blockIdx.y * 64;
    const int t = threadIdx.x;
    const int tr = t >> 6, tc = t & 63;
#pragma unroll
    for (int p = 0; p < 16; ++p)
        tile[p * 4 + tr][tc] = W[(size_t)(k0 + p * 4 + tr) * DD + n0 + tc];
    __syncthreads();
#pragma unroll
    for (int p = 0; p < 16; ++p) {
        const int nn = p * 4 + tr;
        dst[(size_t)(n0 + nn) * DD + k0 + tc] = (_Float16)tile[tc][nn];
    }
}

// fp16 GEMM, 128x128 tile, BK=32, pure async staging, XOR-swizzled LDS.
// MODE 0: A = x16, WT rows 0..1535 ([W_f|W_in|W_g]^T), fused epilogues ->
//         seg0 dm=(1-lb)*sig(-v), seg1 u=silu(v), seg2 g=sig(v)  (fp16)
// MODE 1: A = v,   WT = W_out^T, out = f32 (o0), bias = b0.
template <int MODE>
__global__ __launch_bounds__(256) void gemm_f16(
    const _Float16* __restrict__ A, const _Float16* __restrict__ WT,
    const float* __restrict__ b0, const float* __restrict__ b1,
    const float* __restrict__ b2, const float* __restrict__ lb_ptr,
    void* __restrict__ o0, void* __restrict__ o1, void* __restrict__ o2)
{
    __shared__ __align__(16) _Float16 As[128][32];
    __shared__ __align__(16) _Float16 Bs[128][32];

    const int NB = (MODE == 0) ? 12 : 4;       // n-blocks
    const int lin = blockIdx.x;
    const int xcd = lin & 7;
    const int n_idx = (lin >> 3) % NB;
    const int mq = lin / (8 * NB);
    const int m0 = (xcd + 8 * mq) * 128;       // same XCD -> same A strip
    const int n0 = n_idx * 128;

    const int tid  = threadIdx.x;
    const int wave = tid >> 6;
    const int lane = tid & 63;
    const int wm = wave >> 1, wn = wave & 1;
    const int lrow = lane & 15;
    const int lk   = lane >> 4;

    // async staging: lane -> slot row lane>>2, slot col8 lane&3;
    // source col8 xor-swizzled so LDS[r][c8] = G[r][c8 ^ ((r>>1)&3)]
    const int srow  = lane >> 2;
    const int skoff = ((lane & 3) ^ ((lane >> 3) & 3)) * 8;
    // reader: G[row][lk] = LDS[row][lk ^ ((row>>1)&3)]; (row>>1)&3 == (lrow>>1)&3
    const int ksw = (lk ^ ((lrow >> 1) & 3)) * 8;

    f32x4 acc[4][4];
#pragma unroll
    for (int i = 0; i < 4; ++i)
#pragma unroll
        for (int j = 0; j < 4; ++j) acc[i][j] = (f32x4)(0.f);

    for (int k0 = 0; k0 < DD; k0 += 32) {
#pragma unroll
        for (int i = 0; i < 2; ++i) {
            const int row = wave * 32 + i * 16;
            const _Float16* bsrc = WT + (size_t)(n0 + row + srow) * DD + k0 + skoff;
            __builtin_amdgcn_global_load_lds(
                (const __attribute__((address_space(1))) void*)bsrc,
                (__attribute__((address_space(3))) void*)&Bs[row][0], 16, 0, 0);
            const _Float16* asrc = A + (size_t)(m0 + row + srow) * DD + k0 + skoff;
            __builtin_amdgcn_global_load_lds(
                (const __attribute__((address_space(1))) void*)asrc,
                (__attribute__((address_space(3))) void*)&As[row][0], 16, 0, 0);
        }
        __syncthreads();
        f16x8 afr[4], bfr[4];
#pragma unroll
        for (int t = 0; t < 4; ++t) {
            afr[t] = *(const f16x8*)&As[wm * 64 + t * 16 + lrow][ksw];
            bfr[t] = *(const f16x8*)&Bs[wn * 64 + t * 16 + lrow][ksw];
        }
#pragma unroll
        for (int mt = 0; mt < 4; ++mt)
#pragma unroll
            for (int nt = 0; nt < 4; ++nt)
                acc[mt][nt] = __builtin_amdgcn_mfma_f32_16x16x32_f16(
                    afr[mt], bfr[nt], acc[mt][nt], 0, 0, 0);
        __syncthreads();
    }

    if (MODE == 0) {
        const int seg = n_idx >> 2;
        const float lbv = lb_ptr[0];
        const float* bias = (seg == 0) ? b0 : (seg == 1) ? b1 : b2;
        _Float16* outp = (seg == 0) ? (_Float16*)o0
                       : (seg == 1) ? (_Float16*)o1 : (_Float16*)o2;
        const int cb = (n_idx & 3) * 128 + wn * 64;
#pragma unroll
        for (int mt = 0; mt < 4; ++mt) {
#pragma unroll
            for (int nt = 0; nt < 4; ++nt) {
                const int col = cb + nt * 16 + lrow;
                const float bcol = bias[col];
#pragma unroll
                for (int r = 0; r < 4; ++r) {
                    const int row = m0 + wm * 64 + mt * 16 + lk * 4 + r;
                    const float v = acc[mt][nt][r] + bcol;
                    float res;
                    if (seg == 0)      res = (1.0f - lbv) * sigmoidf_(-v);
                    else if (seg == 1) res = v * sigmoidf_(v);
                    else               res = sigmoidf_(v);
                    outp[(size_t)row * DD + col] = (_Float16)res;
                }
            }
        }
    } else {
        float* outp = (float*)o0;
#pragma unroll
        for (int mt = 0; mt < 4; ++mt) {
#pragma unroll
            for (int nt = 0; nt < 4; ++nt) {
                const int col = n0 + wn * 64 + nt * 16 + lrow;
                const float bcol = b0[col];
#pragma unroll
                for (int r = 0; r < 4; ++r) {
                    const int row = m0 + wm * 64 + mt * 16 + lk * 4 + r;
                    outp[(size_t)row * DD + col] = acc[mt][nt][r] + bcol;
                }
            }
        }
    }
}

// Inclusive fwd+bwd complex gated scan along j. lam = 1-dm, inp = dm*u.
__global__ __launch_bounds__(256) void scan_j(
    const _Float16* __restrict__ dm, const _Float16* __restrict__ u,
    const float* __restrict__ theta, _Float16* __restrict__ hidden)
{
    const int g = blockIdx.x * 256 + threadIdx.x;
    const int d = g & (DD - 1);
    const int line = g >> 9;
    const size_t base = (size_t)line * (HG * DD) + d;
    float s, c;
    sincosf(theta[d], &s, &c);

    float fr[HG];
    float yr = 0.f, yi = 0.f;
#pragma unroll
    for (int j = 0; j < HG; ++j) {
        const size_t idx = base + (size_t)j * DD;
        const float dmv = (float)dm[idx];
        const float lm = 1.0f - dmv;
        const float xv = dmv * (float)u[idx];
        const float nr = fmaf(lm, c * yr - s * yi, xv);
        const float ni = lm * (c * yi + s * yr);
        yr = nr; yi = ni;
        fr[j] = yr;
    }
    yr = 0.f; yi = 0.f;
#pragma unroll
    for (int j = HG - 1; j >= 0; --j) {
        const size_t idx = base + (size_t)j * DD;
        const float dmv = (float)dm[idx];
        const float lm = 1.0f - dmv;
        const float xv = dmv * (float)u[idx];
        const float nr = fmaf(lm, c * yr - s * yi, xv);
        const float ni = lm * (c * yi + s * yr);
        yr = nr; yi = ni;
        hidden[idx] = (_Float16)(fr[j] + yr);
    }
}

// Inclusive fwd+bwd complex gated scan along i, accumulating into hidden.
__global__ __launch_bounds__(256) void scan_i(
    const _Float16* __restrict__ dm, const _Float16* __restrict__ u,
    const float* __restrict__ theta, _Float16* __restrict__ hidden)
{
    const int g = blockIdx.x * 256 + threadIdx.x;
    const int d = g & (DD - 1);
    const int line = g >> 9;
    const int bb = line >> 6;
    const int j = line & 63;
    const size_t base = (size_t)bb * (HG * HG * DD) + (size_t)j * DD + d;
    float s, c;
    sincosf(theta[d], &s, &c);

    float fr[HG];
    float yr = 0.f, yi = 0.f;
#pragma unroll
    for (int i = 0; i < HG; ++i) {
        const size_t idx = base + (size_t)i * (HG * DD);
        const float dmv = (float)dm[idx];
        const float lm = 1.0f - dmv;
        const float xv = dmv * (float)u[idx];
        const float nr = fmaf(lm, c * yr - s * yi, xv);
        const float ni = lm * (c * yi + s * yr);
        yr = nr; yi = ni;
        fr[i] = yr;
    }
    yr = 0.f; yi = 0.f;
#pragma unroll
    for (int i = HG - 1; i >= 0; --i) {
        const size_t idx = base + (size_t)i * (HG * DD);
        const float dmv = (float)dm[idx];
        const float lm = 1.0f - dmv;
        const float xv = dmv * (float)u[idx];
        const float nr = fmaf(lm, c * yr - s * yi, xv);
        const float ni = lm * (c * yi + s * yr);
        yr = nr; yi = ni;
        hidden[idx] = (_Float16)((float)hidden[idx] + fr[i] + yr);
    }
}

// v = g * hidden * rsqrt(mean(hidden^2)+1e-6), fp16 out. One block per row.
__global__ __launch_bounds__(256) void gate_rmsnorm(
    const _Float16* __restrict__ hidden, const _Float16* __restrict__ g,
    _Float16* __restrict__ v)
{
    const int row = blockIdx.x;
    const int t = threadIdx.x;
    const size_t b0 = (size_t)row * DD + t;
    const float h0 = (float)hidden[b0];
    const float h1 = (float)hidden[b0 + 256];
    float ss = h0 * h0 + h1 * h1;
#pragma unroll
    for (int off = 32; off > 0; off >>= 1) ss += __shfl_down(ss, off, 64);
    __shared__ float wsum[4];
    __shared__ float rms_s;
    if ((t & 63) == 0) wsum[t >> 6] = ss;
    __syncthreads();
    if (t == 0) {
        const float tot = wsum[0] + wsum[1] + wsum[2] + wsum[3];
        rms_s = rsqrtf(tot * (1.0f / (float)DD) + 1e-6f);
    }
    __syncthreads();
    const float rms = rms_s;
    v[b0]       = (_Float16)((float)g[b0] * h0 * rms);
    v[b0 + 256] = (_Float16)((float)g[b0 + 256] * h1 * rms);
}

extern "C" void kernel_launch(void* const* d_in, const int* in_sizes, int n_in,
                              void* d_out, int out_size, void* d_ws, size_t ws_size,
                              hipStream_t stream)
{
    const float* x     = (const float*)d_in[0];
    const float* lb    = (const float*)d_in[1];
    const float* W_in  = (const float*)d_in[2];
    const float* b_in  = (const float*)d_in[3];
    const float* W_f   = (const float*)d_in[4];
    const float* b_f   = (const float*)d_in[5];
    const float* theta = (const float*)d_in[6];
    const float* W_g   = (const float*)d_in[7];
    const float* b_g   = (const float*)d_in[8];
    const float* W_out = (const float*)d_in[9];
    const float* b_out = (const float*)d_in[10];

    float* out = (float*)d_out;
    char* wsb  = (char*)d_ws;

    // ws (98 MB): [0,32M) dm fp16 (later v)  [32M,64M) u fp16
    //             [64M,96M) g fp16           [96M,98M) WT fp16 [2048][512]
    _Float16* dm_v = (_Float16*)wsb;
    _Float16* u_b  = (_Float16*)(wsb + ELEMS * 2);
    _Float16* g_b  = (_Float16*)(wsb + ELEMS * 4);
    _Float16* WT   = (_Float16*)(wsb + ELEMS * 6);
    const size_t WSEG = (size_t)DD * DD;

    // d_out (64 MB f32) doubles as scratch: [0,32M) hidden fp16,
    // [32M,64M) x16 fp16. Both dead before the tail GEMM overwrites d_out.
    _Float16* hidden = (_Float16*)d_out;
    _Float16* x16    = (_Float16*)((char*)d_out + ELEMS * 2);

    cvt_x<<<8192, 256, 0, stream>>>(x, x16);
    wtrans4<<<dim3(8, 8, 4), 256, 0, stream>>>(W_f, W_in, W_g, W_out, WT);

    // fused: dm | u | g  (3072 blocks, XCD-swizzled)
    gemm_f16<0><<<3072, 256, 0, stream>>>(x16, WT, b_f, b_in, b_g, lb,
                                          dm_v, u_b, g_b);

    scan_j<<<1024, 256, 0, stream>>>(dm_v, u_b, theta, hidden);
    scan_i<<<1024, 256, 0, stream>>>(dm_v, u_b, theta, hidden);

    // v overwrites dm (dead after scan_i)
    gate_rmsnorm<<<M_ROWS, 256, 0, stream>>>(hidden, g_b, dm_v);

    // out = v @ W_out^T + b_out  (overwrites all of d_out)
    gemm_f16<1><<<1024, 256, 0, stream>>>(dm_v, WT + 3 * WSEG, b_out, nullptr,
                                          nullptr, nullptr, out, nullptr, nullptr);
}

// Round 5
// 341.431 us; speedup vs baseline: 3.6236x; 1.0561x over previous
//
#include <hip/hip_runtime.h>
#include <math.h>

#define DD 512
#define HG 64
#define M_ROWS 32768                    // 8*64*64
#define ELEMS ((size_t)M_ROWS * DD)
#define LOG2E 1.44269504088896340736f

typedef __attribute__((ext_vector_type(8))) _Float16 f16x8;
typedef __attribute__((ext_vector_type(2))) _Float16 f16x2;
typedef __attribute__((ext_vector_type(4))) float f32x4;

__device__ __forceinline__ float fexp2_(float x) { return __builtin_amdgcn_exp2f(x); }
__device__ __forceinline__ float frcp_(float x)  { return __builtin_amdgcn_rcpf(x); }
// sigmoid(v) = 1/(1+exp2(-v*log2e)); inf-safe: exp2->inf => rcp->0
__device__ __forceinline__ float fsig_(float v)  { return frcp_(1.0f + fexp2_(-v * LOG2E)); }

// Fused prep: blocks [0,8192) convert x fp32->fp16; blocks [8192,8448)
// transpose+convert the four 512x512 weights into WT (fp16, N-major).
__global__ __launch_bounds__(256) void prep(
    const float* __restrict__ x, _Float16* __restrict__ x16,
    const float* __restrict__ W0, const float* __restrict__ W1,
    const float* __restrict__ W2, const float* __restrict__ W3,
    _Float16* __restrict__ WT)
{
    __shared__ float tile[64][65];
    if (blockIdx.x < 8192) {
        const size_t i = ((size_t)blockIdx.x * 256 + threadIdx.x) * 8;
        const float4 a = *(const float4*)&x[i];
        const float4 b = *(const float4*)&x[i + 4];
        f16x8 h;
        h[0] = (_Float16)a.x; h[1] = (_Float16)a.y;
        h[2] = (_Float16)a.z; h[3] = (_Float16)a.w;
        h[4] = (_Float16)b.x; h[5] = (_Float16)b.y;
        h[6] = (_Float16)b.z; h[7] = (_Float16)b.w;
        *(f16x8*)&x16[i] = h;
        return;
    }
    const int wb = blockIdx.x - 8192;       // 0..255
    const int z = wb >> 6;
    const int rem = wb & 63;
    const int n0 = (rem & 7) * 64, k0 = (rem >> 3) * 64;
    const float* W = (z == 0) ? W0 : (z == 1) ? W1 : (z == 2) ? W2 : W3;
    _Float16* dst = WT + (size_t)z * DD * DD;
    const int t = threadIdx.x;
    const int tr = t >> 6, tc = t & 63;
#pragma unroll
    for (int p = 0; p < 16; ++p)
        tile[p * 4 + tr][tc] = W[(size_t)(k0 + p * 4 + tr) * DD + n0 + tc];
    __syncthreads();
#pragma unroll
    for (int p = 0; p < 16; ++p) {
        const int nn = p * 4 + tr;
        dst[(size_t)(n0 + nn) * DD + k0 + tc] = (_Float16)tile[tc][nn];
    }
}

// fp16 GEMM, 128x128 tile, BK=64 as two [128][32] XOR-swizzled stages.
// MODE 0: A=x16, WT=[W_f|W_in|W_g]^T (N=1536), epilogues dm/u/g (fp16).
// MODE 1: A=v, WT=W_out^T, out f32.
template <int MODE>
__global__ __launch_bounds__(256) void gemm_f16(
    const _Float16* __restrict__ A, const _Float16* __restrict__ WT,
    const float* __restrict__ b0, const float* __restrict__ b1,
    const float* __restrict__ b2, const float* __restrict__ lb_ptr,
    void* __restrict__ o0, void* __restrict__ o1, void* __restrict__ o2)
{
    __shared__ __align__(16) _Float16 As[2][128][32];
    __shared__ __align__(16) _Float16 Bs[2][128][32];

    const int NB = (MODE == 0) ? 12 : 4;
    const int lin = blockIdx.x;
    const int xcd = lin & 7;
    const int n_idx = (lin >> 3) % NB;
    const int mq = lin / (8 * NB);
    const int m0 = (xcd + 8 * mq) * 128;      // same XCD -> same A strip
    const int n0 = n_idx * 128;

    const int tid  = threadIdx.x;
    const int wave = tid >> 6;
    const int lane = tid & 63;
    const int wm = wave >> 1, wn = wave & 1;
    const int lrow = lane & 15;
    const int lk   = lane >> 4;

    // async staging slot: row lane>>2, col8 lane&3; source col8 XOR-swizzled
    // so LDS[r][c8] = G[r][c8 ^ ((r>>1)&3)]  (proven 0-conflict layout)
    const int srow  = lane >> 2;
    const int skoff = ((lane & 3) ^ ((lane >> 3) & 3)) * 8;
    const int ksw   = (lk ^ ((lrow >> 1) & 3)) * 8;

    f32x4 acc[4][4];
#pragma unroll
    for (int i = 0; i < 4; ++i)
#pragma unroll
        for (int j = 0; j < 4; ++j) acc[i][j] = (f32x4)(0.f);

    for (int k0 = 0; k0 < DD; k0 += 64) {
#pragma unroll
        for (int h = 0; h < 2; ++h) {
#pragma unroll
            for (int i = 0; i < 2; ++i) {
                const int row = wave * 32 + i * 16;
                const _Float16* bsrc =
                    WT + (size_t)(n0 + row + srow) * DD + k0 + h * 32 + skoff;
                __builtin_amdgcn_global_load_lds(
                    (const __attribute__((address_space(1))) void*)bsrc,
                    (__attribute__((address_space(3))) void*)&Bs[h][row][0], 16, 0, 0);
                const _Float16* asrc =
                    A + (size_t)(m0 + row + srow) * DD + k0 + h * 32 + skoff;
                __builtin_amdgcn_global_load_lds(
                    (const __attribute__((address_space(1))) void*)asrc,
                    (__attribute__((address_space(3))) void*)&As[h][row][0], 16, 0, 0);
            }
        }
        __syncthreads();
#pragma unroll
        for (int h = 0; h < 2; ++h) {
            f16x8 afr[4], bfr[4];
#pragma unroll
            for (int t = 0; t < 4; ++t) {
                afr[t] = *(const f16x8*)&As[h][wm * 64 + t * 16 + lrow][ksw];
                bfr[t] = *(const f16x8*)&Bs[h][wn * 64 + t * 16 + lrow][ksw];
            }
#pragma unroll
            for (int mt = 0; mt < 4; ++mt)
#pragma unroll
                for (int nt = 0; nt < 4; ++nt)
                    acc[mt][nt] = __builtin_amdgcn_mfma_f32_16x16x32_f16(
                        afr[mt], bfr[nt], acc[mt][nt], 0, 0, 0);
        }
        __syncthreads();
    }

    if (MODE == 0) {
        const int seg = n_idx >> 2;
        const float lbv = lb_ptr[0];
        const float* bias = (seg == 0) ? b0 : (seg == 1) ? b1 : b2;
        _Float16* outp = (seg == 0) ? (_Float16*)o0
                       : (seg == 1) ? (_Float16*)o1 : (_Float16*)o2;
        const int cb = (n_idx & 3) * 128 + wn * 64;
#pragma unroll
        for (int mt = 0; mt < 4; ++mt) {
#pragma unroll
            for (int nt = 0; nt < 4; ++nt) {
                const int col = cb + nt * 16 + lrow;
                const float bcol = bias[col];
#pragma unroll
                for (int r = 0; r < 4; ++r) {
                    const int row = m0 + wm * 64 + mt * 16 + lk * 4 + r;
                    const float v = acc[mt][nt][r] + bcol;
                    float res;
                    if (seg == 0)      res = (1.0f - lbv) * frcp_(1.0f + fexp2_(v * LOG2E));
                    else if (seg == 1) res = v * fsig_(v);
                    else               res = fsig_(v);
                    outp[(size_t)row * DD + col] = (_Float16)res;
                }
            }
        }
    } else {
        float* outp = (float*)o0;
#pragma unroll
        for (int mt = 0; mt < 4; ++mt) {
#pragma unroll
            for (int nt = 0; nt < 4; ++nt) {
                const int col = n0 + wn * 64 + nt * 16 + lrow;
                const float bcol = b0[col];
#pragma unroll
                for (int r = 0; r < 4; ++r) {
                    const int row = m0 + wm * 64 + mt * 16 + lk * 4 + r;
                    outp[(size_t)row * DD + col] = acc[mt][nt][r] + bcol;
                }
            }
        }
    }
}

// Both bidirectional scans in one launch, 2 d-lanes per thread (f16x2).
// Blocks [0,512): axis-1 (j) scan -> ha.  Blocks [512,1024): axis-0 (i) -> hb.
// lam = 1-dm, inp = dm*u; y <- lam*(c*y) rotated + inp; out = fwd+bwd.
__global__ __launch_bounds__(256) void scan2(
    const _Float16* __restrict__ dm, const _Float16* __restrict__ u,
    const float* __restrict__ theta,
    _Float16* __restrict__ ha, _Float16* __restrict__ hb)
{
    const int t = (blockIdx.x & 511) * 256 + threadIdx.x;   // 0..131071
    const bool is_i = blockIdx.x >= 512;
    const int dp = t & 255;            // d-pair index
    const int line = t >> 8;           // 0..511
    const int d0 = dp * 2;
    size_t base, stride;
    _Float16* hout;
    if (!is_i) {
        base = (size_t)line * (HG * DD) + d0; stride = DD; hout = ha;
    } else {
        const int bb = line >> 6, j = line & 63;
        base = (size_t)bb * (HG * HG * DD) + (size_t)j * DD + d0;
        stride = (size_t)HG * DD; hout = hb;
    }
    float s0, c0, s1, c1;
    sincosf(theta[d0], &s0, &c0);
    sincosf(theta[d0 + 1], &s1, &c1);

    f16x2 fr[HG];
    float yr0 = 0.f, yi0 = 0.f, yr1 = 0.f, yi1 = 0.f;
#pragma unroll
    for (int k = 0; k < HG; ++k) {
        const size_t idx = base + (size_t)k * stride;
        const f16x2 dp2 = *(const f16x2*)&dm[idx];
        const f16x2 up2 = *(const f16x2*)&u[idx];
        const float dm0 = (float)dp2[0], dm1 = (float)dp2[1];
        const float lm0 = 1.0f - dm0, lm1 = 1.0f - dm1;
        float nr = fmaf(lm0, c0 * yr0 - s0 * yi0, dm0 * (float)up2[0]);
        yi0 = lm0 * (c0 * yi0 + s0 * yr0); yr0 = nr;
        nr = fmaf(lm1, c1 * yr1 - s1 * yi1, dm1 * (float)up2[1]);
        yi1 = lm1 * (c1 * yi1 + s1 * yr1); yr1 = nr;
        f16x2 p; p[0] = (_Float16)yr0; p[1] = (_Float16)yr1;
        fr[k] = p;
    }
    yr0 = 0.f; yi0 = 0.f; yr1 = 0.f; yi1 = 0.f;
#pragma unroll
    for (int k = HG - 1; k >= 0; --k) {
        const size_t idx = base + (size_t)k * stride;
        const f16x2 dp2 = *(const f16x2*)&dm[idx];
        const f16x2 up2 = *(const f16x2*)&u[idx];
        const float dm0 = (float)dp2[0], dm1 = (float)dp2[1];
        const float lm0 = 1.0f - dm0, lm1 = 1.0f - dm1;
        float nr = fmaf(lm0, c0 * yr0 - s0 * yi0, dm0 * (float)up2[0]);
        yi0 = lm0 * (c0 * yi0 + s0 * yr0); yr0 = nr;
        nr = fmaf(lm1, c1 * yr1 - s1 * yi1, dm1 * (float)up2[1]);
        yi1 = lm1 * (c1 * yi1 + s1 * yr1); yr1 = nr;
        f16x2 o;
        o[0] = (_Float16)((float)fr[k][0] + yr0);
        o[1] = (_Float16)((float)fr[k][1] + yr1);
        *(f16x2*)&hout[idx] = o;
    }
}

// v = g * (ha+hb) * rsqrt(mean((ha+hb)^2)+1e-6), fp16. One block per row.
__global__ __launch_bounds__(256) void gate_rmsnorm(
    const _Float16* __restrict__ ha, const _Float16* __restrict__ hb,
    const _Float16* __restrict__ g, _Float16* __restrict__ v)
{
    const int row = blockIdx.x;
    const int t = threadIdx.x;
    const size_t b0 = (size_t)row * DD + t * 2;
    const f16x2 a = *(const f16x2*)&ha[b0];
    const f16x2 b = *(const f16x2*)&hb[b0];
    const float h0 = (float)a[0] + (float)b[0];
    const float h1 = (float)a[1] + (float)b[1];
    float ss = h0 * h0 + h1 * h1;
#pragma unroll
    for (int off = 32; off > 0; off >>= 1) ss += __shfl_down(ss, off, 64);
    __shared__ float wsum[4];
    __shared__ float rms_s;
    if ((t & 63) == 0) wsum[t >> 6] = ss;
    __syncthreads();
    if (t == 0) {
        const float tot = wsum[0] + wsum[1] + wsum[2] + wsum[3];
        rms_s = rsqrtf(tot * (1.0f / (float)DD) + 1e-6f);
    }
    __syncthreads();
    const float rms = rms_s;
    const f16x2 gg = *(const f16x2*)&g[b0];
    f16x2 o;
    o[0] = (_Float16)((float)gg[0] * h0 * rms);
    o[1] = (_Float16)((float)gg[1] * h1 * rms);
    *(f16x2*)&v[b0] = o;
}

extern "C" void kernel_launch(void* const* d_in, const int* in_sizes, int n_in,
                              void* d_out, int out_size, void* d_ws, size_t ws_size,
                              hipStream_t stream)
{
    const float* x     = (const float*)d_in[0];
    const float* lb    = (const float*)d_in[1];
    const float* W_in  = (const float*)d_in[2];
    const float* b_in  = (const float*)d_in[3];
    const float* W_f   = (const float*)d_in[4];
    const float* b_f   = (const float*)d_in[5];
    const float* theta = (const float*)d_in[6];
    const float* W_g   = (const float*)d_in[7];
    const float* b_g   = (const float*)d_in[8];
    const float* W_out = (const float*)d_in[9];
    const float* b_out = (const float*)d_in[10];

    float* out = (float*)d_out;
    char* wsb  = (char*)d_ws;

    // ws (98 MB): [0,32M) dm fp16 (later v)  [32M,64M) u fp16
    //             [64M,96M) g fp16           [96M,98M) WT fp16 [2048][512]
    _Float16* dm_v = (_Float16*)wsb;
    _Float16* u_b  = (_Float16*)(wsb + ELEMS * 2);
    _Float16* g_b  = (_Float16*)(wsb + ELEMS * 4);
    _Float16* WT   = (_Float16*)(wsb + ELEMS * 6);
    const size_t WSEG = (size_t)DD * DD;

    // d_out doubles as scratch: [0,32M) ha fp16; [32M,64M) x16, then hb fp16.
    _Float16* ha  = (_Float16*)d_out;
    _Float16* x16 = (_Float16*)((char*)d_out + ELEMS * 2);
    _Float16* hb  = x16;                 // x16 dead after gemm_f16<0>

    prep<<<8448, 256, 0, stream>>>(x, x16, W_f, W_in, W_g, W_out, WT);

    gemm_f16<0><<<3072, 256, 0, stream>>>(x16, WT, b_f, b_in, b_g, lb,
                                          dm_v, u_b, g_b);

    scan2<<<1024, 256, 0, stream>>>(dm_v, u_b, theta, ha, hb);

    // v overwrites dm (dead after scan2)
    gate_rmsnorm<<<M_ROWS, 256, 0, stream>>>(ha, hb, g_b, dm_v);

    // out = v @ W_out^T + b_out  (overwrites all of d_out)
    gemm_f16<1><<<1024, 256, 0, stream>>>(dm_v, WT + 3 * WSEG, b_out, nullptr,
                                          nullptr, nullptr, out, nullptr, nullptr);
}